// Round 9
// baseline (964.056 us; speedup 1.0000x reference)
//
#include <hip/hip_runtime.h>

// Social-LSTM trajectory model, v9 (= v8 with the Af u64-offset bug fixed).
// Encoder LSTM(2->32->64): persistent bf16-MFMA kernel (v6, measured 261 us).
// Decoder LSTM(96->256): ONE persistent kernel (plain launch, 256 blocks,
// 80 KB LDS -> guaranteed co-resident), hand-rolled grid barrier via
// device-scope atomics, h exchanged through Infinity Cache with
// __hip_atomic_* AGENT-scope ops (immune to per-XCD L2 staleness).

#define S_TOT 86016   // 4096 hist + 81920 nbrs
#define NB    4096
#define NNB   81920
#define TT    16
#define NFUT  24
#define HXS   104     // encoder LDS row stride in bf16 (16B-aligned rows)
#define L2E   1.44269504088896f

typedef __attribute__((ext_vector_type(8)))  short short8v;
typedef __attribute__((ext_vector_type(16))) float f32x16;
typedef unsigned long long u64;

__device__ __forceinline__ float rcpf(float x) { return __builtin_amdgcn_rcpf(x); }
// a is pre-scaled by log2e: sigmoid(x) = 1/(1+2^(-x*log2e))
__device__ __forceinline__ float sigm2(float a)  { return rcpf(1.0f + exp2f(-a)); }
// a is pre-scaled by 2*log2e: tanh(x) = 1 - 2/(2^(2x*log2e)+1)
__device__ __forceinline__ float tanh2(float a)  { return 1.0f - 2.0f * rcpf(exp2f(a) + 1.0f); }
__device__ __forceinline__ float tanhx(float x)  { return tanh2(x * (2.0f * L2E)); }
__device__ __forceinline__ float lrelu(float v)  { return v >= 0.0f ? v : 0.1f * v; }
__device__ __forceinline__ short f2bf(float f) {            // RNE fp32->bf16
    unsigned u = __float_as_uint(f);
    unsigned r = (u + 0x7fffu + ((u >> 16) & 1u)) >> 16;
    return (short)r;
}

// coherent (Infinity-Cache) accessors: bypass per-XCD L2
__device__ __forceinline__ u64 ic_load_u64(const u64* p) {
    return __hip_atomic_load(p, __ATOMIC_RELAXED, __HIP_MEMORY_SCOPE_AGENT);
}
__device__ __forceinline__ void ic_store_u32(unsigned* p, unsigned v) {
    __hip_atomic_store(p, v, __ATOMIC_RELAXED, __HIP_MEMORY_SCOPE_AGENT);
}

// ===========================================================================
// ENCODER (v6, measured good)
// ===========================================================================
__global__ __launch_bounds__(64) void k_pack_encB(
    const float* __restrict__ wih, const float* __restrict__ whh,
    const float* __restrict__ bih, const float* __restrict__ bhh,
    short* __restrict__ pB, float* __restrict__ pbias)
{
    const int fi = blockIdx.x;          // 0..47
    const int cc = fi % 6, gg = fi / 6;
    const int gate = gg & 3, H = gg >> 2;
    const int lane = threadIdx.x;       // 0..63
    const int row  = gate * 64 + H * 32 + (lane & 31);
    const float sc = (gate == 2) ? 2.0f * L2E : L2E;
    short8v v;
#pragma unroll
    for (int u = 0; u < 8; u++) {
        const int k = cc * 16 + (lane >> 5) * 8 + u;
        const float f = (k < 32) ? wih[row * 32 + k] : whh[row * 64 + (k - 32)];
        v[u] = f2bf(f * sc);
    }
    *(short8v*)&pB[((size_t)fi * 64 + lane) * 8] = v;
    if (cc == 0 && lane < 32)
        pbias[H * 128 + gate * 32 + lane] = (bih[row] + bhh[row]) * sc;
}

__global__ __launch_bounds__(256, 2) void k_encoder(
    const float* __restrict__ ctx_raw,  // (T, B, 2)
    const float* __restrict__ nbr_raw,  // (T, N, 2)
    const float* __restrict__ ipw, const float* __restrict__ ipb,
    const short* __restrict__ pB, const float* __restrict__ pbias,
    float* __restrict__ hfin)           // [S_TOT][64]
{
    __shared__ short hx2[2 * 64 * HXS];
    const int tid  = threadIdx.x;
    const int lane = tid & 63;
    const int w    = __builtin_amdgcn_readfirstlane(tid >> 6);  // 0..3
    const int H    = w >> 1;
    const int M0   = (w & 1) * 32;
    const int seq_base = blockIdx.x * 64;
    const bool is_hist = (seq_base < NB);

    short8v Bf[4][6];
#pragma unroll
    for (int gate = 0; gate < 4; gate++)
#pragma unroll
        for (int cc = 0; cc < 6; cc++)
            Bf[gate][cc] = *(const short8v*)
                &pB[(((size_t)(H * 4 + gate) * 6 + cc) * 64 + lane) * 8];

    float b4[4];
#pragma unroll
    for (int gate = 0; gate < 4; gate++)
        b4[gate] = pbias[H * 128 + gate * 32 + (lane & 31)];

    // zero buffer-0 h region (k 32..95)
    {
        short8v z;
#pragma unroll
        for (int u = 0; u < 8; u++) z[u] = 0;
        for (int i = tid; i < 64 * 8; i += 256)
            *(short8v*)&hx2[(i >> 3) * HXS + 32 + (i & 7) * 8] = z;
    }

    const int sx = seq_base + (tid & 63);
    float2 f2;
    {
        const float* rp = is_hist ? &ctx_raw[(size_t)sx * 2]
                                  : &nbr_raw[(size_t)(sx - NB) * 2];
        f2 = *(const float2*)rp;
        const int k0 = (tid >> 6) * 8;
        short8v xv;
#pragma unroll
        for (int u = 0; u < 8; u++) {
            const int xj = k0 + u;
            xv[u] = f2bf(lrelu(ipb[xj] + ipw[xj * 2] * f2.x + ipw[xj * 2 + 1] * f2.y));
        }
        *(short8v*)&hx2[(tid & 63) * HXS + k0] = xv;
    }
    __syncthreads();

    float cst[16];
#pragma unroll
    for (int r = 0; r < 16; r++) cst[r] = 0.0f;

    const int aoff = (M0 + (lane & 31)) * HXS + (lane >> 5) * 8;
    const int hcol = 32 + H * 32 + (lane & 31);

#pragma unroll 1
    for (int t = 0; t < TT; t++) {
        short* cur = hx2 + (t & 1) * (64 * HXS);
        short* nxt = hx2 + ((t + 1) & 1) * (64 * HXS);

        float2 f2n = f2;
        if (t < TT - 1) {
            const float* rp = is_hist
                ? &ctx_raw[((size_t)(t + 1) * NB + sx) * 2]
                : &nbr_raw[((size_t)(t + 1) * NNB + (sx - NB)) * 2];
            f2n = *(const float2*)rp;
        }

        short8v Af[6];
#pragma unroll
        for (int cc = 0; cc < 6; cc++)
            Af[cc] = *(const short8v*)&cur[aoff + cc * 16];

        f32x16 C[4];
#pragma unroll
        for (int gate = 0; gate < 4; gate++)
#pragma unroll
            for (int r = 0; r < 16; r++) C[gate][r] = b4[gate];

#pragma unroll
        for (int cc = 0; cc < 6; cc++)
#pragma unroll
            for (int gate = 0; gate < 4; gate++)
                C[gate] = __builtin_amdgcn_mfma_f32_32x32x16_bf16(
                    Af[cc], Bf[gate][cc], C[gate], 0, 0, 0);

        float hn[16];
#pragma unroll
        for (int r = 0; r < 16; r++) {
            const float iv = sigm2(C[0][r]);
            const float fv = sigm2(C[1][r]);
            const float gv = tanh2(C[2][r]);
            const float ov = sigm2(C[3][r]);
            const float cn = fv * cst[r] + iv * gv;
            cst[r] = cn;
            hn[r] = ov * tanhx(cn);
        }

        if (t < TT - 1) {
#pragma unroll
            for (int r = 0; r < 16; r++) {
                const int row = (r & 3) + 8 * (r >> 2) + 4 * (lane >> 5);
                nxt[(M0 + row) * HXS + hcol] = f2bf(hn[r]);
            }
            const int k0 = (tid >> 6) * 8;
            short8v xv;
#pragma unroll
            for (int u = 0; u < 8; u++) {
                const int xj = k0 + u;
                xv[u] = f2bf(lrelu(ipb[xj] + ipw[xj * 2] * f2n.x + ipw[xj * 2 + 1] * f2n.y));
            }
            *(short8v*)&nxt[(tid & 63) * HXS + k0] = xv;
            __syncthreads();   // single barrier per step
            f2 = f2n;
        } else {
#pragma unroll
            for (int r = 0; r < 16; r++) {
                const int row = (r & 3) + 8 * (r >> 2) + 4 * (lane >> 5);
                hfin[(size_t)(seq_base + M0 + row) * 64 + H * 32 + (lane & 31)] = hn[r];
            }
        }
    }
}

// ===========================================================================
// ATTENTION (unchanged)
// ===========================================================================
__global__ __launch_bounds__(256) void k_attn(
    const float* __restrict__ h_enc,    // [S_TOT][64]
    const float* __restrict__ dynw, const float* __restrict__ dynb,
    const float* __restrict__ l1w,  const float* __restrict__ l1b,
    float* __restrict__ ctx)            // [B][96]
{
    const int b   = blockIdx.x;
    const int tid = threadIdx.x;
    __shared__ float sh_he[32];
    __shared__ float sh_soc[20][65];
    __shared__ float sh_e[20];

    if (tid < 32) {
        float a = dynb[tid];
        const float* w  = &dynw[tid * 64];
        const float* hb = &h_enc[(size_t)b * 64];
#pragma unroll 8
        for (int k = 0; k < 64; k++) a += w[k] * hb[k];
        a = lrelu(a);
        sh_he[tid] = a;
        ctx[b * 96 + tid] = a;
    }
    for (int idx = tid; idx < 20 * 64; idx += 256) {
        const int g = idx >> 6, k = idx & 63;
        sh_soc[g][k] = h_enc[(size_t)(NB + b * 20 + g) * 64 + k];
    }
    __syncthreads();

    if (tid < 20) {
        float e = l1b[0];
#pragma unroll
        for (int m = 0; m < 32; m++) e += l1w[m] * tanhx(sh_he[m]);
#pragma unroll 8
        for (int k = 0; k < 64; k++) e += l1w[32 + k] * tanhx(sh_soc[tid][k]);
        sh_e[tid] = e;
    }
    __syncthreads();

    if (tid < 64) {
        float mx = -1e30f;
#pragma unroll
        for (int g = 0; g < 20; g++) mx = fmaxf(mx, sh_e[g]);
        float wgt[20];
        float sm = 0.0f;
#pragma unroll
        for (int g = 0; g < 20; g++) { wgt[g] = exp2f((sh_e[g] - mx) * L2E); sm += wgt[g]; }
        const float inv = 1.0f / sm;
        float a = 0.0f;
#pragma unroll
        for (int g = 0; g < 20; g++) a += wgt[g] * sh_soc[g][tid];
        ctx[b * 96 + 32 + tid] = a * inv;
    }
}

// ===========================================================================
// DECODER
// ===========================================================================
// Weight pack (exp2 scale folded): pBd[hg][cc][gate][lane][8] bf16,
// row = gate*256 + hg*32 + (lane&31), k = cc*16 + (lane>>5)*8 + u.
// opwB[cc][lane][8] unscaled.
__global__ __launch_bounds__(256) void k_pack_decB(
    const float* __restrict__ whh,   // (1024,256)
    const float* __restrict__ opw,   // (5,256)
    short* __restrict__ pBd, short* __restrict__ opwB)
{
    const int bid  = blockIdx.x;     // 0..127 = hg*16+cc ; 128..143 = opw cc
    const int tid  = threadIdx.x;
    const int lane = tid & 63;
    if (bid < 128) {
        const int gate = tid >> 6;
        const int hg = bid >> 4, cc = bid & 15;
        const int row  = gate * 256 + hg * 32 + (lane & 31);
        const int kb   = cc * 16 + (lane >> 5) * 8;
        const float sc = (gate == 2) ? 2.0f * L2E : L2E;
        short8v v;
#pragma unroll
        for (int u = 0; u < 8; u++) v[u] = f2bf(whh[row * 256 + kb + u] * sc);
        *(short8v*)&pBd[((size_t)(bid * 4 + gate) * 64 + lane) * 8] = v;
    } else if (tid < 64) {
        const int cc = bid - 128;
        const int n  = lane & 31, kb = cc * 16 + (lane >> 5) * 8;
        short8v v;
#pragma unroll
        for (int u = 0; u < 8; u++)
            v[u] = (n < 5) ? f2bf(opw[n * 256 + kb + u]) : (short)0;
        *(short8v*)&opwB[(cc * 64 + lane) * 8] = v;
    }
}

// Input-gate GEMM -> pgx[agent][j][gate] float4-packed, exp2 scale folded.
__global__ __launch_bounds__(256) void k_gx(
    const float* __restrict__ ctx,
    const float* __restrict__ wih,
    const float* __restrict__ bih, const float* __restrict__ bhh,
    float* __restrict__ pgx)            // [NB][256][4]
{
    const int lane = threadIdx.x & 63;
    const int s    = blockIdx.x * 64 + lane;
    const int jq   = __builtin_amdgcn_readfirstlane(blockIdx.y * 4 + (threadIdx.x >> 6));
    const int j0   = jq * 4;
    float acc[4];
#pragma unroll
    for (int d = 0; d < 4; d++) acc[d] = bih[j0 + d] + bhh[j0 + d];
    const float* c = &ctx[(size_t)s * 96];
    for (int k0 = 0; k0 < 96; k0 += 8) {
        float cb[8];
#pragma unroll
        for (int u = 0; u < 8; u++) cb[u] = c[k0 + u];
#pragma unroll
        for (int d = 0; d < 4; d++) {
            const float* w = &wih[(j0 + d) * 96 + k0];
#pragma unroll
            for (int u = 0; u < 8; u++) acc[d] += w[u] * cb[u];
        }
    }
#pragma unroll
    for (int d = 0; d < 4; d++) {
        const int row = j0 + d;
        const int g = row >> 8, j = row & 255;
        const float sc = (g == 2) ? 2.0f * L2E : L2E;
        pgx[(((size_t)s << 8) + j) * 4 + g] = acc[d] * sc;
    }
}

// Persistent decoder, plain launch. 256 blocks = 32 agent-groups x 8
// hidden-groups; block = 4 waves x 32 agents. LDS 80 KB (weights 64 + head
// 16) -> 2 blocks/CU capacity -> all 256 guaranteed co-resident. Grid
// barrier: per-step zeroed counter + acq/rel atomics. h exchanged via
// AGENT-scope atomic u32 stores / u64 loads (Infinity-Cache coherent).
__global__ __launch_bounds__(256, 1) void k_dec_persist(
    const float* __restrict__ pgx,    // [NB][256][4]
    const short* __restrict__ pBd,    // [8][16][4][64][8] bf16
    const short* __restrict__ opwB,   // [16][64][8] bf16
    const float* __restrict__ opb,
    short* __restrict__ hb0, short* __restrict__ hb1,  // [NB][256] bf16
    unsigned* __restrict__ cnt,       // [NFUT] zeroed each launch
    float* __restrict__ out)
{
    __shared__ short ldsB[16 * 4 * 64 * 8];   // 64 KB
    __shared__ short ldsO[16 * 64 * 8];       // 16 KB
    const int tid  = threadIdx.x;
    const int lane = tid & 63;
    const int bx   = blockIdx.x;
    const int hg   = bx & 7;                  // 0..7
    const int ag   = bx >> 3;                 // 0..31
    const int j0   = hg * 32;
    const int Ab   = ag * 128;
    const int Mb   = Ab + (tid >> 6) * 32;    // wave's global agent base
    const bool headblk = (hg == 0);
    const int arow_base = (tid >> 6) * 32 + 4 * (lane >> 5);
    const int n    = lane & 31;

    // --- one-time staging ---
    {
        const short* src = pBd + (size_t)hg * 32768;
        for (int it = 0; it < 16; it++) {
            const int idx = it * 256 + tid;
            *(short8v*)&ldsB[idx * 8] = *(const short8v*)&src[(size_t)idx * 8];
        }
        if (headblk)
            for (int it = 0; it < 4; it++) {
                const int idx = it * 256 + tid;
                *(short8v*)&ldsO[idx * 8] = *(const short8v*)&opwB[idx * 8];
            }
    }
    __syncthreads();

    float cst[16];
#pragma unroll
    for (int r = 0; r < 16; r++) cst[r] = 0.0f;

    short* bufs[2] = {hb0, hb1};

#pragma unroll 1
    for (int t = 0; t < NFUT; t++) {
        const short* h_in = bufs[t & 1];
        short* h_out      = bufs[(t + 1) & 1];

        f32x16 C[4], Ch;
#pragma unroll
        for (int g = 0; g < 4; g++)
#pragma unroll
            for (int r = 0; r < 16; r++) C[g][r] = 0.0f;
#pragma unroll
        for (int r = 0; r < 16; r++) Ch[r] = 0.0f;

        if (t > 0) {
            // prefetch A-fragments through the coherent path (IC).
            // A-frag: m = Mb+n, k = (lane>>5)*8 + u  ->  (lane>>5)*2 u64s!
            const u64* hq = (const u64*)(h_in + ((size_t)(Mb + n) << 8))
                            + (lane >> 5) * 2;
            u64 aq0[16], aq1[16];
#pragma unroll
            for (int cc = 0; cc < 16; cc++) {
                aq0[cc] = ic_load_u64(hq + cc * 4);
                aq1[cc] = ic_load_u64(hq + cc * 4 + 1);
            }
#pragma unroll
            for (int cc = 0; cc < 16; cc++) {
                union { u64 q[2]; short8v v; } uu;
                uu.q[0] = aq0[cc]; uu.q[1] = aq1[cc];
                const short8v Af = uu.v;
#pragma unroll
                for (int g = 0; g < 4; g++) {
                    const short8v Bf = *(short8v*)&ldsB[((cc * 4 + g) * 64 + lane) * 8];
                    C[g] = __builtin_amdgcn_mfma_f32_32x32x16_bf16(Af, Bf, C[g], 0, 0, 0);
                }
                if (headblk) {
                    const short8v Of = *(short8v*)&ldsO[(cc * 64 + lane) * 8];
                    Ch = __builtin_amdgcn_mfma_f32_32x32x16_bf16(Af, Of, Ch, 0, 0, 0);
                }
            }
        }

        // pointwise: lane owns hidden j = j0+n, 16 agent rows; pack lane^1
        // pairs into u32 and store via IC (even lanes only)
#pragma unroll
        for (int r = 0; r < 16; r++) {
            const int al = arow_base + (r & 3) + 8 * (r >> 2);
            const float4 g4 = *(const float4*)&pgx[(((size_t)(Ab + al) << 8) + j0 + n) * 4];
            const float iv = sigm2(C[0][r] + g4.x);
            const float fv = sigm2(C[1][r] + g4.y);
            const float gv = tanh2(C[2][r] + g4.z);
            const float ov = sigm2(C[3][r] + g4.w);
            const float cn = fv * cst[r] + iv * gv;
            cst[r] = cn;
            const int sv = (int)(unsigned short)f2bf(ov * tanhx(cn));
            const int ovv = __shfl_xor(sv, 1);
            if (!(lane & 1)) {
                unsigned* dst = (unsigned*)&h_out[((size_t)(Ab + al) << 8) + j0 + n];
                ic_store_u32(dst, (unsigned)sv | ((unsigned)ovv << 16));
            }
        }

        // output head for step t-1 (from h_in = h_t)
        if (t > 0 && headblk && n < 5) {
            const float ob = opb[n];
#pragma unroll
            for (int r = 0; r < 16; r++) {
                const int agent = Mb + (r & 3) + 8 * (r >> 2) + 4 * (lane >> 5);
                float v = Ch[r] + ob;
                if (n == 2 || n == 3) v = exp2f(v * L2E);
                else if (n == 4) v = tanhx(v);
                out[(size_t)agent * (NFUT * 5) + (t - 1) * 5 + n] = v;
            }
        }

        // grid barrier: fresh counter per step, acq/rel device-scope atomics
        __syncthreads();            // drains this block's stores (vmcnt 0)
        if (tid == 0) {
            __threadfence();
            __hip_atomic_fetch_add(&cnt[t], 1u, __ATOMIC_ACQ_REL,
                                   __HIP_MEMORY_SCOPE_AGENT);
            while (__hip_atomic_load(&cnt[t], __ATOMIC_ACQUIRE,
                                     __HIP_MEMORY_SCOPE_AGENT) < 256u)
                __builtin_amdgcn_s_sleep(8);
        }
        __syncthreads();
    }

    // final head: out[23] from h_24 = bufs[NFUT & 1]
    if (headblk) {
        const short* h_in = bufs[NFUT & 1];
        f32x16 Ch;
#pragma unroll
        for (int r = 0; r < 16; r++) Ch[r] = 0.0f;
        const u64* hq = (const u64*)(h_in + ((size_t)(Mb + n) << 8))
                        + (lane >> 5) * 2;
#pragma unroll 4
        for (int cc = 0; cc < 16; cc++) {
            union { u64 q[2]; short8v v; } uu;
            uu.q[0] = ic_load_u64(hq + cc * 4);
            uu.q[1] = ic_load_u64(hq + cc * 4 + 1);
            const short8v Of = *(short8v*)&ldsO[(cc * 64 + lane) * 8];
            Ch = __builtin_amdgcn_mfma_f32_32x32x16_bf16(uu.v, Of, Ch, 0, 0, 0);
        }
        if (n < 5) {
            const float ob = opb[n];
#pragma unroll
            for (int r = 0; r < 16; r++) {
                const int agent = Mb + (r & 3) + 8 * (r >> 2) + 4 * (lane >> 5);
                float v = Ch[r] + ob;
                if (n == 2 || n == 3) v = exp2f(v * L2E);
                else if (n == 4) v = tanhx(v);
                out[(size_t)agent * (NFUT * 5) + (NFUT - 1) * 5 + n] = v;
            }
        }
    }
}

extern "C" void kernel_launch(void* const* d_in, const int* in_sizes, int n_in,
                              void* d_out, int out_size, void* d_ws, size_t ws_size,
                              hipStream_t stream)
{
    // 0:x 1:beta 2:context 3:nbrs 4:mask 5:ip_w 6:ip_b 7:enc_wih 8:enc_whh
    // 9:enc_bih 10:enc_bhh 11:dyn_w 12:dyn_b 13:lin1_w 14:lin1_b 15:dec_wih
    // 16:dec_whh 17:dec_bih 18:dec_bhh 19:op_w 20:op_b
    const float* ctx_raw = (const float*)d_in[2];
    const float* nbr_raw = (const float*)d_in[3];
    const float* ipw     = (const float*)d_in[5];
    const float* ipb     = (const float*)d_in[6];
    const float* enc_wih = (const float*)d_in[7];
    const float* enc_whh = (const float*)d_in[8];
    const float* enc_bih = (const float*)d_in[9];
    const float* enc_bhh = (const float*)d_in[10];
    const float* dynw    = (const float*)d_in[11];
    const float* dynb    = (const float*)d_in[12];
    const float* l1w     = (const float*)d_in[13];
    const float* l1b     = (const float*)d_in[14];
    const float* dec_wih = (const float*)d_in[15];
    const float* dec_whh = (const float*)d_in[16];
    const float* dec_bih = (const float*)d_in[17];
    const float* dec_bhh = (const float*)d_in[18];
    const float* opw     = (const float*)d_in[19];
    const float* opb     = (const float*)d_in[20];
    float* out = (float*)d_out;

    // workspace carve-up (~45 MB)
    char* pc = (char*)d_ws;
    float* hfin  = (float*)pc; pc += (size_t)S_TOT * 64 * 4;
    float* ctxb  = (float*)pc; pc += (size_t)NB * 96 * 4;
    float* pgx   = (float*)pc; pc += (size_t)NB * 1024 * 4;
    float* pbias = (float*)pc; pc += 256 * 4;
    short* hD0   = (short*)pc; pc += (size_t)NB * 256 * 2;
    short* hD1   = (short*)pc; pc += (size_t)NB * 256 * 2;
    short* pB    = (short*)pc; pc += (size_t)48 * 64 * 8 * 2;
    short* pBd   = (short*)pc; pc += (size_t)8 * 16 * 4 * 64 * 8 * 2;
    short* opwB  = (short*)pc; pc += (size_t)16 * 64 * 8 * 2;
    unsigned* cnt = (unsigned*)pc; pc += 64 * 4;

    hipMemsetAsync(cnt, 0, 64 * sizeof(unsigned), stream);

    k_pack_encB<<<dim3(48), 64, 0, stream>>>(enc_wih, enc_whh, enc_bih, enc_bhh,
                                             pB, pbias);
    k_pack_decB<<<dim3(144), 256, 0, stream>>>(dec_whh, opw, pBd, opwB);

    k_encoder<<<dim3(S_TOT / 64), 256, 0, stream>>>(
        ctx_raw, nbr_raw, ipw, ipb, pB, pbias, hfin);

    k_attn<<<dim3(NB), 256, 0, stream>>>(hfin, dynw, dynb, l1w, l1b, ctxb);

    k_gx<<<dim3(NB / 64, 64), 256, 0, stream>>>(ctxb, dec_wih, dec_bih, dec_bhh, pgx);

    k_dec_persist<<<dim3(256), 256, 0, stream>>>(
        pgx, pBd, opwB, opb, hD0, hD1, cnt, out);
}

// Round 11
// 581.889 us; speedup vs baseline: 1.6568x; 1.6568x over previous
//
#include <hip/hip_runtime.h>

// Social-LSTM trajectory model, v11 (= v10 with BIJECTIVE LDS swizzle fix).
// Encoder LSTM(2->32->64): persistent bf16-MFMA kernel, 2-wave/32-seq blocks.
// Decoder LSTM(96->256): ONE persistent kernel, block = 32 agents x ALL 256
// hidden (8 waves). h exchange intra-block via LDS, double-buffered,
// column-XOR swizzle (bijective within each 512B row).

#define S_TOT 86016   // 4096 hist + 81920 nbrs
#define NB    4096
#define NNB   81920
#define TT    16
#define NFUT  24
#define HXS   104     // encoder LDS row stride in bf16 (16B-aligned rows)
#define L2E   1.44269504088896f

typedef __attribute__((ext_vector_type(8)))  short short8v;
typedef __attribute__((ext_vector_type(16))) float f32x16;

__device__ __forceinline__ float rcpf(float x) { return __builtin_amdgcn_rcpf(x); }
// a is pre-scaled by log2e: sigmoid(x) = 1/(1+2^(-x*log2e))
__device__ __forceinline__ float sigm2(float a)  { return rcpf(1.0f + exp2f(-a)); }
// a is pre-scaled by 2*log2e: tanh(x) = 1 - 2/(2^(2x*log2e)+1)
__device__ __forceinline__ float tanh2(float a)  { return 1.0f - 2.0f * rcpf(exp2f(a) + 1.0f); }
__device__ __forceinline__ float tanhx(float x)  { return tanh2(x * (2.0f * L2E)); }
__device__ __forceinline__ float lrelu(float v)  { return v >= 0.0f ? v : 0.1f * v; }
__device__ __forceinline__ short f2bf(float f) {            // RNE fp32->bf16
    unsigned u = __float_as_uint(f);
    unsigned r = (u + 0x7fffu + ((u >> 16) & 1u)) >> 16;
    return (short)r;
}

// ===========================================================================
// ENCODER
// ===========================================================================
__global__ __launch_bounds__(64) void k_pack_encB(
    const float* __restrict__ wih, const float* __restrict__ whh,
    const float* __restrict__ bih, const float* __restrict__ bhh,
    short* __restrict__ pB, float* __restrict__ pbias)
{
    const int fi = blockIdx.x;          // 0..47
    const int cc = fi % 6, gg = fi / 6;
    const int gate = gg & 3, H = gg >> 2;
    const int lane = threadIdx.x;       // 0..63
    const int row  = gate * 64 + H * 32 + (lane & 31);
    const float sc = (gate == 2) ? 2.0f * L2E : L2E;
    short8v v;
#pragma unroll
    for (int u = 0; u < 8; u++) {
        const int k = cc * 16 + (lane >> 5) * 8 + u;
        const float f = (k < 32) ? wih[row * 32 + k] : whh[row * 64 + (k - 32)];
        v[u] = f2bf(f * sc);
    }
    *(short8v*)&pB[((size_t)fi * 64 + lane) * 8] = v;
    if (cc == 0 && lane < 32)
        pbias[H * 128 + gate * 32 + lane] = (bih[row] + bhh[row]) * sc;
}

// Persistent MFMA encoder. Block = 32 seqs, 2 waves; wave w = n-half H=w.
// Double-buffered LDS, ONE barrier per step. 2688 blocks.
__global__ __launch_bounds__(128) void k_encoder(
    const float* __restrict__ ctx_raw,  // (T, B, 2)
    const float* __restrict__ nbr_raw,  // (T, N, 2)
    const float* __restrict__ ipw, const float* __restrict__ ipb,
    const short* __restrict__ pB, const float* __restrict__ pbias,
    float* __restrict__ hfin)           // [S_TOT][64]
{
    __shared__ short hx2[2 * 32 * HXS];
    const int tid  = threadIdx.x;
    const int lane = tid & 63;
    const int H    = __builtin_amdgcn_readfirstlane(tid >> 6);  // 0..1
    const int seq_base = blockIdx.x * 32;
    const bool is_hist = (seq_base < NB);   // uniform (32 | NB)

    short8v Bf[4][6];
#pragma unroll
    for (int gate = 0; gate < 4; gate++)
#pragma unroll
        for (int cc = 0; cc < 6; cc++)
            Bf[gate][cc] = *(const short8v*)
                &pB[(((size_t)(H * 4 + gate) * 6 + cc) * 64 + lane) * 8];

    float b4[4];
#pragma unroll
    for (int gate = 0; gate < 4; gate++)
        b4[gate] = pbias[H * 128 + gate * 32 + (lane & 31)];

    // zero buffer-0 h region (k 32..95): 32 seqs x 64 k
    {
        short8v z;
#pragma unroll
        for (int u = 0; u < 8; u++) z[u] = 0;
        for (int i = tid; i < 32 * 8; i += 128)
            *(short8v*)&hx2[(i >> 3) * HXS + 32 + (i & 7) * 8] = z;
    }

    // x(t=0) into buffer 0: thread covers seq = tid&31, k-chunk (tid>>5)*8
    const int sx = seq_base + (tid & 31);
    float2 f2;
    {
        const float* rp = is_hist ? &ctx_raw[(size_t)sx * 2]
                                  : &nbr_raw[(size_t)(sx - NB) * 2];
        f2 = *(const float2*)rp;
        const int k0 = (tid >> 5) * 8;
        short8v xv;
#pragma unroll
        for (int u = 0; u < 8; u++) {
            const int xj = k0 + u;
            xv[u] = f2bf(lrelu(ipb[xj] + ipw[xj * 2] * f2.x + ipw[xj * 2 + 1] * f2.y));
        }
        *(short8v*)&hx2[(tid & 31) * HXS + k0] = xv;
    }
    __syncthreads();

    float cst[16];
#pragma unroll
    for (int r = 0; r < 16; r++) cst[r] = 0.0f;

    const int aoff = (lane & 31) * HXS + (lane >> 5) * 8;
    const int hcol = 32 + H * 32 + (lane & 31);

#pragma unroll 1
    for (int t = 0; t < TT; t++) {
        short* cur = hx2 + (t & 1) * (32 * HXS);
        short* nxt = hx2 + ((t + 1) & 1) * (32 * HXS);

        float2 f2n = f2;
        if (t < TT - 1) {
            const float* rp = is_hist
                ? &ctx_raw[((size_t)(t + 1) * NB + sx) * 2]
                : &nbr_raw[((size_t)(t + 1) * NNB + (sx - NB)) * 2];
            f2n = *(const float2*)rp;
        }

        short8v Af[6];
#pragma unroll
        for (int cc = 0; cc < 6; cc++)
            Af[cc] = *(const short8v*)&cur[aoff + cc * 16];

        f32x16 C[4];
#pragma unroll
        for (int gate = 0; gate < 4; gate++)
#pragma unroll
            for (int r = 0; r < 16; r++) C[gate][r] = b4[gate];

#pragma unroll
        for (int cc = 0; cc < 6; cc++)
#pragma unroll
            for (int gate = 0; gate < 4; gate++)
                C[gate] = __builtin_amdgcn_mfma_f32_32x32x16_bf16(
                    Af[cc], Bf[gate][cc], C[gate], 0, 0, 0);

        float hn[16];
#pragma unroll
        for (int r = 0; r < 16; r++) {
            const float iv = sigm2(C[0][r]);
            const float fv = sigm2(C[1][r]);
            const float gv = tanh2(C[2][r]);
            const float ov = sigm2(C[3][r]);
            const float cn = fv * cst[r] + iv * gv;
            cst[r] = cn;
            hn[r] = ov * tanhx(cn);
        }

        if (t < TT - 1) {
#pragma unroll
            for (int r = 0; r < 16; r++) {
                const int row = (r & 3) + 8 * (r >> 2) + 4 * (lane >> 5);
                nxt[row * HXS + hcol] = f2bf(hn[r]);
            }
            const int k0 = (tid >> 5) * 8;
            short8v xv;
#pragma unroll
            for (int u = 0; u < 8; u++) {
                const int xj = k0 + u;
                xv[u] = f2bf(lrelu(ipb[xj] + ipw[xj * 2] * f2n.x + ipw[xj * 2 + 1] * f2n.y));
            }
            *(short8v*)&nxt[(tid & 31) * HXS + k0] = xv;
            __syncthreads();   // single barrier per step
            f2 = f2n;
        } else {
#pragma unroll
            for (int r = 0; r < 16; r++) {
                const int row = (r & 3) + 8 * (r >> 2) + 4 * (lane >> 5);
                hfin[(size_t)(seq_base + row) * 64 + H * 32 + (lane & 31)] = hn[r];
            }
        }
    }
}

// ===========================================================================
// ATTENTION (unchanged)
// ===========================================================================
__global__ __launch_bounds__(256) void k_attn(
    const float* __restrict__ h_enc,    // [S_TOT][64]
    const float* __restrict__ dynw, const float* __restrict__ dynb,
    const float* __restrict__ l1w,  const float* __restrict__ l1b,
    float* __restrict__ ctx)            // [B][96]
{
    const int b   = blockIdx.x;
    const int tid = threadIdx.x;
    __shared__ float sh_he[32];
    __shared__ float sh_soc[20][65];
    __shared__ float sh_e[20];

    if (tid < 32) {
        float a = dynb[tid];
        const float* w  = &dynw[tid * 64];
        const float* hb = &h_enc[(size_t)b * 64];
#pragma unroll 8
        for (int k = 0; k < 64; k++) a += w[k] * hb[k];
        a = lrelu(a);
        sh_he[tid] = a;
        ctx[b * 96 + tid] = a;
    }
    for (int idx = tid; idx < 20 * 64; idx += 256) {
        const int g = idx >> 6, k = idx & 63;
        sh_soc[g][k] = h_enc[(size_t)(NB + b * 20 + g) * 64 + k];
    }
    __syncthreads();

    if (tid < 20) {
        float e = l1b[0];
#pragma unroll
        for (int m = 0; m < 32; m++) e += l1w[m] * tanhx(sh_he[m]);
#pragma unroll 8
        for (int k = 0; k < 64; k++) e += l1w[32 + k] * tanhx(sh_soc[tid][k]);
        sh_e[tid] = e;
    }
    __syncthreads();

    if (tid < 64) {
        float mx = -1e30f;
#pragma unroll
        for (int g = 0; g < 20; g++) mx = fmaxf(mx, sh_e[g]);
        float wgt[20];
        float sm = 0.0f;
#pragma unroll
        for (int g = 0; g < 20; g++) { wgt[g] = exp2f((sh_e[g] - mx) * L2E); sm += wgt[g]; }
        const float inv = 1.0f / sm;
        float a = 0.0f;
#pragma unroll
        for (int g = 0; g < 20; g++) a += wgt[g] * sh_soc[g][tid];
        ctx[b * 96 + 32 + tid] = a * inv;
    }
}

// ===========================================================================
// DECODER
// ===========================================================================
__global__ __launch_bounds__(256) void k_pack_decB(
    const float* __restrict__ whh,   // (1024,256)
    const float* __restrict__ opw,   // (5,256)
    short* __restrict__ pBd, short* __restrict__ opwB)
{
    const int bid  = blockIdx.x;     // 0..127 = hg*16+cc ; 128..143 = opw cc
    const int tid  = threadIdx.x;
    const int lane = tid & 63;
    if (bid < 128) {
        const int gate = tid >> 6;
        const int hg = bid >> 4, cc = bid & 15;
        const int row  = gate * 256 + hg * 32 + (lane & 31);
        const int kb   = cc * 16 + (lane >> 5) * 8;
        const float sc = (gate == 2) ? 2.0f * L2E : L2E;
        short8v v;
#pragma unroll
        for (int u = 0; u < 8; u++) v[u] = f2bf(whh[row * 256 + kb + u] * sc);
        *(short8v*)&pBd[((size_t)(bid * 4 + gate) * 64 + lane) * 8] = v;
    } else if (tid < 64) {
        const int cc = bid - 128;
        const int n  = lane & 31, kb = cc * 16 + (lane >> 5) * 8;
        short8v v;
#pragma unroll
        for (int u = 0; u < 8; u++)
            v[u] = (n < 5) ? f2bf(opw[n * 256 + kb + u]) : (short)0;
        *(short8v*)&opwB[(cc * 64 + lane) * 8] = v;
    }
}

// Input-gate GEMM -> pgx[agent][j][gate] float4-packed, exp2 scale folded.
__global__ __launch_bounds__(256) void k_gx(
    const float* __restrict__ ctx,
    const float* __restrict__ wih,
    const float* __restrict__ bih, const float* __restrict__ bhh,
    float* __restrict__ pgx)            // [NB][256][4]
{
    const int lane = threadIdx.x & 63;
    const int s    = blockIdx.x * 64 + lane;
    const int jq   = __builtin_amdgcn_readfirstlane(blockIdx.y * 4 + (threadIdx.x >> 6));
    const int j0   = jq * 4;
    float acc[4];
#pragma unroll
    for (int d = 0; d < 4; d++) acc[d] = bih[j0 + d] + bhh[j0 + d];
    const float* c = &ctx[(size_t)s * 96];
    for (int k0 = 0; k0 < 96; k0 += 8) {
        float cb[8];
#pragma unroll
        for (int u = 0; u < 8; u++) cb[u] = c[k0 + u];
#pragma unroll
        for (int d = 0; d < 4; d++) {
            const float* w = &wih[(j0 + d) * 96 + k0];
#pragma unroll
            for (int u = 0; u < 8; u++) acc[d] += w[u] * cb[u];
        }
    }
#pragma unroll
    for (int d = 0; d < 4; d++) {
        const int row = j0 + d;
        const int g = row >> 8, j = row & 255;
        const float sc = (g == 2) ? 2.0f * L2E : L2E;
        pgx[(((size_t)s << 8) + j) * 4 + g] = acc[d] * sc;
    }
}

// Persistent decoder. 128 blocks x 512 threads; block owns 32 agents x ALL
// 256 hidden. Wave w = hidden-group w (4 gates x 32 j). h double-buffered in
// LDS with COLUMN-XOR swizzle (bijective: addr = row*512 + (col ^ ((row&7)<<4))),
// ONE __syncthreads per step. Weights streamed from L2 (same addresses each
// step -> resident). c in registers. Head fused as extra MFMA on wave 0.
__global__ __launch_bounds__(512, 2) void k_dec_persist(
    const float* __restrict__ pgx,    // [NB][256][4]
    const short* __restrict__ pBd,    // [8][16][4][64][8] bf16
    const short* __restrict__ opwB,   // [16][64][8] bf16
    const float* __restrict__ opb,
    float* __restrict__ out)
{
    __shared__ short hbuf[2][32 * 256];   // 2 x 16 KB
    const int tid  = threadIdx.x;
    const int lane = tid & 63;
    const int w    = __builtin_amdgcn_readfirstlane(tid >> 6);  // 0..7 = hg
    const int Ab   = blockIdx.x * 32;
    const int n    = lane & 31;
    const int hl   = lane >> 5;           // 0/1
    const bool headw = (w == 0);

    // per-lane weight bases (L2-resident)
    const short* wb = pBd + (size_t)w * 32768 + (size_t)lane * 8;  // +(cc*4+g)*512
    const short* ob = opwB + (size_t)lane * 8;                     // +cc*512

    float cst[16];
#pragma unroll
    for (int r = 0; r < 16; r++) cst[r] = 0.0f;

#pragma unroll 1
    for (int t = 0; t < NFUT; t++) {
        const char* cur = (const char*)hbuf[t & 1];
        char* nxt       = (char*)hbuf[(t + 1) & 1];

        f32x16 C[4], Ch;
#pragma unroll
        for (int g = 0; g < 4; g++)
#pragma unroll
            for (int r = 0; r < 16; r++) C[g][r] = 0.0f;
#pragma unroll
        for (int r = 0; r < 16; r++) Ch[r] = 0.0f;

        if (t > 0) {
#pragma unroll 4
            for (int cc = 0; cc < 16; cc++) {
                // Af: agent row m=n, col bytes = cc*32 + hl*16; bijective XOR
                const int abyte = n * 512 + ((cc * 32 + hl * 16) ^ ((n & 7) << 4));
                const short8v Af = *(const short8v*)(cur + abyte);
#pragma unroll
                for (int g = 0; g < 4; g++) {
                    const short8v Bf = *(const short8v*)&wb[(size_t)(cc * 4 + g) * 512];
                    C[g] = __builtin_amdgcn_mfma_f32_32x32x16_bf16(Af, Bf, C[g], 0, 0, 0);
                }
                if (headw) {
                    const short8v Of = *(const short8v*)&ob[(size_t)cc * 512];
                    Ch = __builtin_amdgcn_mfma_f32_32x32x16_bf16(Af, Of, Ch, 0, 0, 0);
                }
            }
        }

        // pointwise: lane owns hidden j = 32w+n, 16 agent rows
#pragma unroll
        for (int r = 0; r < 16; r++) {
            const int al = (r & 3) + 8 * (r >> 2) + 4 * hl;   // 0..31
            const float4 g4 = *(const float4*)
                &pgx[(((size_t)(Ab + al) << 8) + w * 32 + n) * 4];
            const float iv = sigm2(C[0][r] + g4.x);
            const float fv = sigm2(C[1][r] + g4.y);
            const float gv = tanh2(C[2][r] + g4.z);
            const float ov = sigm2(C[3][r] + g4.w);
            const float cn = fv * cst[r] + iv * gv;
            cst[r] = cn;
            const int hbyte = al * 512 + (((w * 32 + n) * 2) ^ ((al & 7) << 4));
            *(short*)(nxt + hbyte) = f2bf(ov * tanhx(cn));
        }

        // output head for step t-1 (from h_t = cur)
        if (t > 0 && headw && n < 5) {
            const float obias = opb[n];
#pragma unroll
            for (int r = 0; r < 16; r++) {
                const int agent = Ab + (r & 3) + 8 * (r >> 2) + 4 * hl;
                float v = Ch[r] + obias;
                if (n == 2 || n == 3) v = exp2f(v * L2E);
                else if (n == 4) v = tanhx(v);
                out[(size_t)agent * (NFUT * 5) + (t - 1) * 5 + n] = v;
            }
        }

        __syncthreads();
    }

    // final head: out[23] from h_24 = hbuf[NFUT & 1] (= hbuf[0])
    if (headw) {
        const char* cur = (const char*)hbuf[NFUT & 1];
        f32x16 Ch;
#pragma unroll
        for (int r = 0; r < 16; r++) Ch[r] = 0.0f;
#pragma unroll 4
        for (int cc = 0; cc < 16; cc++) {
            const int abyte = n * 512 + ((cc * 32 + hl * 16) ^ ((n & 7) << 4));
            const short8v Af = *(const short8v*)(cur + abyte);
            const short8v Of = *(const short8v*)&ob[(size_t)cc * 512];
            Ch = __builtin_amdgcn_mfma_f32_32x32x16_bf16(Af, Of, Ch, 0, 0, 0);
        }
        if (n < 5) {
            const float obias = opb[n];
#pragma unroll
            for (int r = 0; r < 16; r++) {
                const int agent = Ab + (r & 3) + 8 * (r >> 2) + 4 * hl;
                float v = Ch[r] + obias;
                if (n == 2 || n == 3) v = exp2f(v * L2E);
                else if (n == 4) v = tanhx(v);
                out[(size_t)agent * (NFUT * 5) + (NFUT - 1) * 5 + n] = v;
            }
        }
    }
}

extern "C" void kernel_launch(void* const* d_in, const int* in_sizes, int n_in,
                              void* d_out, int out_size, void* d_ws, size_t ws_size,
                              hipStream_t stream)
{
    // 0:x 1:beta 2:context 3:nbrs 4:mask 5:ip_w 6:ip_b 7:enc_wih 8:enc_whh
    // 9:enc_bih 10:enc_bhh 11:dyn_w 12:dyn_b 13:lin1_w 14:lin1_b 15:dec_wih
    // 16:dec_whh 17:dec_bih 18:dec_bhh 19:op_w 20:op_b
    const float* ctx_raw = (const float*)d_in[2];
    const float* nbr_raw = (const float*)d_in[3];
    const float* ipw     = (const float*)d_in[5];
    const float* ipb     = (const float*)d_in[6];
    const float* enc_wih = (const float*)d_in[7];
    const float* enc_whh = (const float*)d_in[8];
    const float* enc_bih = (const float*)d_in[9];
    const float* enc_bhh = (const float*)d_in[10];
    const float* dynw    = (const float*)d_in[11];
    const float* dynb    = (const float*)d_in[12];
    const float* l1w     = (const float*)d_in[13];
    const float* l1b     = (const float*)d_in[14];
    const float* dec_wih = (const float*)d_in[15];
    const float* dec_whh = (const float*)d_in[16];
    const float* dec_bih = (const float*)d_in[17];
    const float* dec_bhh = (const float*)d_in[18];
    const float* opw     = (const float*)d_in[19];
    const float* opb     = (const float*)d_in[20];
    float* out = (float*)d_out;

    // workspace carve-up (~40 MB)
    char* pc = (char*)d_ws;
    float* hfin  = (float*)pc; pc += (size_t)S_TOT * 64 * 4;
    float* ctxb  = (float*)pc; pc += (size_t)NB * 96 * 4;
    float* pgx   = (float*)pc; pc += (size_t)NB * 1024 * 4;
    float* pbias = (float*)pc; pc += 256 * 4;
    short* pB    = (short*)pc; pc += (size_t)48 * 64 * 8 * 2;
    short* pBd   = (short*)pc; pc += (size_t)8 * 16 * 4 * 64 * 8 * 2;
    short* opwB  = (short*)pc; pc += (size_t)16 * 64 * 8 * 2;

    k_pack_encB<<<dim3(48), 64, 0, stream>>>(enc_wih, enc_whh, enc_bih, enc_bhh,
                                             pB, pbias);
    k_pack_decB<<<dim3(144), 256, 0, stream>>>(dec_whh, opw, pBd, opwB);

    k_encoder<<<dim3(S_TOT / 32), 128, 0, stream>>>(
        ctx_raw, nbr_raw, ipw, ipb, pB, pbias, hfin);

    k_attn<<<dim3(NB), 256, 0, stream>>>(hfin, dynw, dynb, l1w, l1b, ctxb);

    k_gx<<<dim3(NB / 64, 64), 256, 0, stream>>>(ctxb, dec_wih, dec_bih, dec_bhh, pgx);

    k_dec_persist<<<dim3(NB / 32), 512, 0, stream>>>(pgx, pBd, opwB, opb, out);
}